// Round 3
// baseline (312.535 us; speedup 1.0000x reference)
//
#include <hip/hip_runtime.h>
#include <stdint.h>

// Problem constants
#define M_BATCH 32768
#define N_OUT   1024
#define K_IN    1024

typedef __attribute__((ext_vector_type(8))) short  short8;
typedef __attribute__((ext_vector_type(4))) float  f32x4;

__device__ __forceinline__ unsigned short f2bf(float f) {
    __bf16 h = (__bf16)f;
    return __builtin_bit_cast(unsigned short, h);
}

typedef const __attribute__((address_space(1))) unsigned int* gas_ptr;
typedef __attribute__((address_space(3))) unsigned int*       las_ptr;

__device__ __forceinline__ void gload_lds16(const void* g, void* l) {
    // async global->LDS, 16B/lane; LDS dest = wave-uniform base + lane*16
    __builtin_amdgcn_global_load_lds((gas_ptr)g, (las_ptr)l, 16, 0, 0);
}

// ---------------------------------------------------------------------------
// Kernel 0: x (f32) -> bf16, grid-stride, 8 elems/thread/iter.
// ---------------------------------------------------------------------------
__global__ __launch_bounds__(256) void cvt_x(const float* __restrict__ x,
                                             unsigned short* __restrict__ xb) {
    const size_t total8 = (size_t)M_BATCH * K_IN / 8;
    const size_t stride = (size_t)gridDim.x * 256;
    for (size_t i = (size_t)blockIdx.x * 256 + threadIdx.x; i < total8; i += stride) {
        f32x4 v0 = *reinterpret_cast<const f32x4*>(x + i * 8);
        f32x4 v1 = *reinterpret_cast<const f32x4*>(x + i * 8 + 4);
        short8 b;
#pragma unroll
        for (int j = 0; j < 4; ++j) b[j]     = (short)f2bf(v0[j]);
#pragma unroll
        for (int j = 0; j < 4; ++j) b[j + 4] = (short)f2bf(v1[j]);
        *reinterpret_cast<short8*>(xb + i * 8) = b;
    }
}

// ---------------------------------------------------------------------------
// Kernel 1: materialize W (bf16) from eigens.
// W[y*8+j][xb*8+c] = eigens[y][xb][(j-c)&7]
// ---------------------------------------------------------------------------
__global__ __launch_bounds__(256) void build_w(const float* __restrict__ eig,
                                               unsigned short* __restrict__ W) {
    int tid = blockIdx.x * 256 + threadIdx.x;   // 0..16383
    int y  = tid >> 7;
    int xb = tid & 127;
    const float* e = eig + (size_t)((y << 7) + xb) * 8;
    f32x4 e0 = *reinterpret_cast<const f32x4*>(e);
    f32x4 e1 = *reinterpret_cast<const f32x4*>(e + 4);
    float ev[8] = {e0[0], e0[1], e0[2], e0[3], e1[0], e1[1], e1[2], e1[3]};
#pragma unroll
    for (int j = 0; j < 8; ++j) {
        alignas(16) unsigned short wv[8];
#pragma unroll
        for (int c = 0; c < 8; ++c) wv[c] = f2bf(ev[(j - c) & 7]);
        *reinterpret_cast<uint4*>(W + (size_t)(y * 8 + j) * K_IN + xb * 8) =
            *reinterpret_cast<const uint4*>(wv);
    }
}

// ---------------------------------------------------------------------------
// Kernel 2 (fast path): deep-pipelined 256x256 GEMM, BK=32, 8 waves (2Mx4N),
// 4-deep circular LDS buffer, counted vmcnt (never 0 in main loop), raw
// s_barrier, setprio around MFMA cluster.
//
// Pipeline invariant entering iteration t (after prev barrier):
//   - tiles <= t fully landed in LDS (all waves)
//   - in-flight: tiles t+1, t+2 (8 loads/wave)
// Iteration t: stage tile t+3 -> buf[(t+3)&3] (== buf[(t-1)&3], whose readers
// all passed the previous barrier); compute buf[t&3]; vmcnt(8) leaves exactly
// tiles t+2,t+3 in flight => tile t+1 landed; barrier.
// ---------------------------------------------------------------------------
#define BM 256
#define BN 256
#define BK 32
#define NT (K_IN / BK)   // 32

__global__ __launch_bounds__(512, 2) void gemm_pipe(const unsigned short* __restrict__ A,
                                                    const unsigned short* __restrict__ W,
                                                    float* __restrict__ C) {
    __shared__ unsigned short Alds[4][BM * BK];  // 4 x 16 KiB
    __shared__ unsigned short Blds[4][BN * BK];  // 4 x 16 KiB  (128 KiB total)

    // XCD-aware bijective swizzle: nwg=512 (%8==0). Consecutive swz on one XCD
    // share the A M-panel (4 N-blocks each) and W (2 MiB) L2-fits per XCD.
    const int bid  = blockIdx.x;                 // 0..511
    const int swz  = (bid & 7) * 64 + (bid >> 3);
    const int nblk = swz & 3;
    const int mblk = swz >> 2;
    const int brow = mblk * BM;
    const int bcol = nblk * BN;

    const int tid  = threadIdx.x;
    const int lane = tid & 63;
    const int w    = tid >> 6;                   // wave 0..7
    const int wm   = w >> 2;                     // 0..1 : M half  (128 rows)
    const int wn   = w & 3;                      // 0..3 : N quarter (64 cols)

    // ---- staging geometry: 1 KiB/wave-inst = 16 rows x 64 B. Wave w covers
    // rows [w*32, w*32+32) of both A and B tiles (2 insts each).
    // Swizzle (16B chunks, 4/row): LDS[row][d] = G[row][d ^ ((row>>1)&3)].
    // Lane l: row_in_seg = l>>2 -> (row>>1)&3 = (l>>3)&3; dest slot = l&3.
    const int srow   = lane >> 2;                          // 0..15
    const int schunk = (lane & 3) ^ ((lane >> 3) & 3);     // swizzled src chunk
    const unsigned short* Ag0 = A + (size_t)(brow + w * 32 +  0 + srow) * K_IN + schunk * 8;
    const unsigned short* Ag1 = A + (size_t)(brow + w * 32 + 16 + srow) * K_IN + schunk * 8;
    const unsigned short* Bg0 = W + (size_t)(bcol + w * 32 +  0 + srow) * K_IN + schunk * 8;
    const unsigned short* Bg1 = W + (size_t)(bcol + w * 32 + 16 + srow) * K_IN + schunk * 8;
    const int ldsOff0 = (w * 32 +  0) * BK;      // element offset of seg 0
    const int ldsOff1 = (w * 32 + 16) * BK;

    auto stage = [&](int tt) {
        const int b  = tt & 3;
        const int kt = tt * BK;
        gload_lds16(Ag0 + kt, &Alds[b][ldsOff0]);
        gload_lds16(Ag1 + kt, &Alds[b][ldsOff1]);
        gload_lds16(Bg0 + kt, &Blds[b][ldsOff0]);
        gload_lds16(Bg1 + kt, &Blds[b][ldsOff1]);
    };

    f32x4 acc[8][4];
    const f32x4 zero = {0.f, 0.f, 0.f, 0.f};
#pragma unroll
    for (int i = 0; i < 8; ++i)
#pragma unroll
        for (int j = 0; j < 4; ++j) acc[i][j] = zero;

    // ---- fragment read geometry. MFMA 16x16x32: lane reads row (lane&15),
    // k-chunk kc = lane>>4 (16 B). Swizzled slot = kc ^ ((row>>1)&3); row bits
    // 1-2 come from (lane&15) only (tile offsets are multiples of 16), so the
    // slot is lane-constant across all fragments.
    const int kc   = lane >> 4;
    const int slot = kc ^ ((lane >> 1) & 3);
    const int arow = wm * 128 + (lane & 15);     // local A row base
    const int brow_b = wn * 64 + (lane & 15);    // local B row (C col) base

    auto compute = [&](int b) {
        short8 bfr[4];
#pragma unroll
        for (int nt = 0; nt < 4; ++nt)
            bfr[nt] = *reinterpret_cast<const short8*>(
                &Blds[b][(brow_b + nt * 16) * BK + slot * 8]);
        short8 af[8];
#pragma unroll
        for (int mt = 0; mt < 8; ++mt)
            af[mt] = *reinterpret_cast<const short8*>(
                &Alds[b][(arow + mt * 16) * BK + slot * 8]);
        __builtin_amdgcn_s_setprio(1);
#pragma unroll
        for (int mt = 0; mt < 8; ++mt)
#pragma unroll
            for (int nt = 0; nt < 4; ++nt)
                acc[mt][nt] = __builtin_amdgcn_mfma_f32_16x16x32_bf16(
                    af[mt], bfr[nt], acc[mt][nt], 0, 0, 0);
        __builtin_amdgcn_s_setprio(0);
    };

    // ---- prologue: 3 tiles in flight, wait for tile 0 (12 -> 8 outstanding)
    stage(0); stage(1); stage(2);
    asm volatile("s_waitcnt vmcnt(8)" ::: "memory");
    __builtin_amdgcn_s_barrier();
    __builtin_amdgcn_sched_barrier(0);

    // ---- main loop: counted vmcnt(8) = tiles t+2,t+3 stay in flight
    for (int t = 0; t < NT - 3; ++t) {
        stage(t + 3);
        compute(t & 3);
        asm volatile("s_waitcnt vmcnt(8)" ::: "memory");
        __builtin_amdgcn_s_barrier();
        __builtin_amdgcn_sched_barrier(0);
    }
    // ---- epilogue drain: 8 -> 4 -> 0
    compute((NT - 3) & 3);
    asm volatile("s_waitcnt vmcnt(4)" ::: "memory");
    __builtin_amdgcn_s_barrier();
    __builtin_amdgcn_sched_barrier(0);
    compute((NT - 2) & 3);
    asm volatile("s_waitcnt vmcnt(0)" ::: "memory");
    __builtin_amdgcn_s_barrier();
    __builtin_amdgcn_sched_barrier(0);
    compute((NT - 1) & 3);

    // ---- epilogue: C/D layout col = lane&15, row = (lane>>4)*4 + reg
#pragma unroll
    for (int mt = 0; mt < 8; ++mt) {
#pragma unroll
        for (int nt = 0; nt < 4; ++nt) {
            int col = bcol + wn * 64 + nt * 16 + (lane & 15);
#pragma unroll
            for (int r = 0; r < 4; ++r) {
                int row = brow + wm * 128 + mt * 16 + (lane >> 4) * 4 + r;
                C[(size_t)row * N_OUT + col] = acc[mt][nt][r];
            }
        }
    }
}

// ---------------------------------------------------------------------------
// Fallback GEMM (round-1 verified): f32 A reg-staged, used if ws too small.
// ---------------------------------------------------------------------------
#define FBM 128
#define FBN 128
#define FBK 64
__global__ __launch_bounds__(256) void gemm_bt(const float* __restrict__ A,
                                               const unsigned short* __restrict__ W,
                                               float* __restrict__ C) {
    __shared__ unsigned short Alds[FBM * FBK];
    __shared__ unsigned short Blds[FBN * FBK];

    const int bid  = blockIdx.x;
    const int swz  = (bid & 7) * 256 + (bid >> 3);
    const int nblk = swz & 7;
    const int mblk = swz >> 3;
    const int brow = mblk * FBM;
    const int bcol = nblk * FBN;

    const int tid  = threadIdx.x;
    const int lane = tid & 63;
    const int wv   = tid >> 6;
    const int wm   = wv >> 1;
    const int wn   = wv & 1;

    f32x4 acc[4][4];
    const f32x4 zero = {0.f, 0.f, 0.f, 0.f};
#pragma unroll
    for (int i = 0; i < 4; ++i)
#pragma unroll
        for (int j = 0; j < 4; ++j) acc[i][j] = zero;

    const int srow  = tid >> 3;
    const int sslot = tid & 7;
    const int sk8   = sslot ^ (srow & 7);
    const float*          Abase = A + (size_t)(brow + srow) * K_IN + sk8 * 8;
    const unsigned short* Wbase = W + (size_t)(bcol + srow) * K_IN + sk8 * 8;
    unsigned short* AldsW = Alds + srow * FBK + sslot * 8;
    unsigned short* BldsW = Blds + srow * FBK + sslot * 8;

    for (int kt = 0; kt < K_IN; kt += FBK) {
        __syncthreads();
#pragma unroll
        for (int it = 0; it < 4; ++it) {
            const float* src = Abase + (size_t)it * 32 * K_IN + kt;
            f32x4 v0 = *reinterpret_cast<const f32x4*>(src);
            f32x4 v1 = *reinterpret_cast<const f32x4*>(src + 4);
            short8 b;
#pragma unroll
            for (int i = 0; i < 4; ++i) b[i]     = (short)f2bf(v0[i]);
#pragma unroll
            for (int i = 0; i < 4; ++i) b[i + 4] = (short)f2bf(v1[i]);
            *reinterpret_cast<short8*>(AldsW + it * 32 * FBK) = b;
        }
#pragma unroll
        for (int it = 0; it < 4; ++it) {
            const unsigned short* src = Wbase + (size_t)it * 32 * K_IN + kt;
            short8 b = *reinterpret_cast<const short8*>(src);
            *reinterpret_cast<short8*>(BldsW + it * 32 * FBK) = b;
        }
        __syncthreads();
#pragma unroll
        for (int ks = 0; ks < 2; ++ks) {
            short8 af[4], bfr[4];
            const int cb = ks * 4 + (lane >> 4);
#pragma unroll
            for (int mt = 0; mt < 4; ++mt) {
                int row  = wm * 64 + mt * 16 + (lane & 15);
                int slot = cb ^ (row & 7);
                af[mt] = *reinterpret_cast<const short8*>(Alds + row * FBK + slot * 8);
            }
#pragma unroll
            for (int nt = 0; nt < 4; ++nt) {
                int row  = wn * 64 + nt * 16 + (lane & 15);
                int slot = cb ^ (row & 7);
                bfr[nt] = *reinterpret_cast<const short8*>(Blds + row * FBK + slot * 8);
            }
#pragma unroll
            for (int mt = 0; mt < 4; ++mt)
#pragma unroll
                for (int nt = 0; nt < 4; ++nt)
                    acc[mt][nt] = __builtin_amdgcn_mfma_f32_16x16x32_bf16(
                        af[mt], bfr[nt], acc[mt][nt], 0, 0, 0);
        }
    }

#pragma unroll
    for (int mt = 0; mt < 4; ++mt) {
#pragma unroll
        for (int nt = 0; nt < 4; ++nt) {
            int col = bcol + wn * 64 + nt * 16 + (lane & 15);
#pragma unroll
            for (int r = 0; r < 4; ++r) {
                int row = brow + wm * 64 + mt * 16 + (lane >> 4) * 4 + r;
                C[(size_t)row * N_OUT + col] = acc[mt][nt][r];
            }
        }
    }
}

extern "C" void kernel_launch(void* const* d_in, const int* in_sizes, int n_in,
                              void* d_out, int out_size, void* d_ws, size_t ws_size,
                              hipStream_t stream) {
    const float* x   = (const float*)d_in[0];    // [32768,1024] f32
    const float* eig = (const float*)d_in[1];    // [128,128,8]  f32
    float* out = (float*)d_out;                  // [32768,1024] f32

    const size_t XB     = (size_t)M_BATCH * K_IN;
    const size_t W_ELTS = (size_t)N_OUT * K_IN;
    const size_t need   = (XB + W_ELTS) * sizeof(unsigned short);

    if (ws_size >= need) {
        unsigned short* xb = (unsigned short*)d_ws;
        unsigned short* W  = (unsigned short*)d_ws + XB;
        hipLaunchKernelGGL(build_w, dim3(64), dim3(256), 0, stream, eig, W);
        hipLaunchKernelGGL(cvt_x, dim3(2048), dim3(256), 0, stream, x, xb);
        hipLaunchKernelGGL(gemm_pipe, dim3((M_BATCH / BM) * (N_OUT / BN)), dim3(512),
                           0, stream, xb, W, out);
    } else if (ws_size >= W_ELTS * sizeof(unsigned short)) {
        unsigned short* W = (unsigned short*)d_ws;
        hipLaunchKernelGGL(build_w, dim3(64), dim3(256), 0, stream, eig, W);
        hipLaunchKernelGGL(gemm_bt, dim3((M_BATCH / FBM) * (N_OUT / FBN)), dim3(256),
                           0, stream, x, W, out);
    }
}